// Round 1
// baseline (105.157 us; speedup 1.0000x reference)
//
#include <hip/hip_runtime.h>

// x: [B=16, C=64, H=256, W=256] fp32
// out: LL [16,64,128,128] ++ high_freq [16,3,64,128,128]  (flat fp32)
//
// Each thread: one 1x4 output quad (i, j..j+3) for one (b,c):
//   reads rows 2i, 2i+1 at cols 8j..8j+7 (2x float4 per row),
//   writes float4 to LL, LH, HL, HH.

#define B_  16
#define C_  64
#define HO  128
#define WO  128
#define WQ  (WO / 4)                       // 32 quads per output row
#define BC  (B_ * C_)                      // 1024
#define TOTAL_QUADS ((long long)BC * HO * WQ)   // 4,194,304
#define HBASE ((long long)BC * HO * WO)         // 16,777,216 (LL size)
#define KSTRIDE ((long long)C_ * HO * WO)       // 1,048,576 (per-k stride in high_freq)

__global__ __launch_bounds__(256) void haar_dwt2_kernel(
    const float* __restrict__ x, float* __restrict__ out)
{
    for (long long t = (long long)blockIdx.x * blockDim.x + threadIdx.x;
         t < TOTAL_QUADS;
         t += (long long)gridDim.x * blockDim.x)
    {
        const int jq = (int)(t % WQ);
        long long r  = t / WQ;
        const int i  = (int)(r % HO);
        const int bc = (int)(r / HO);          // b*64 + c

        // input: row pair (2i, 2i+1), 8 consecutive floats starting at col 8*jq
        const float* row0 = x + (((long long)bc * 256 + 2 * i) * 256) + (jq << 3);
        const float* row1 = row0 + 256;

        const float4 r0a = *(const float4*)(row0);
        const float4 r0b = *(const float4*)(row0 + 4);
        const float4 r1a = *(const float4*)(row1);
        const float4 r1b = *(const float4*)(row1 + 4);

        const float r0[8] = {r0a.x, r0a.y, r0a.z, r0a.w, r0b.x, r0b.y, r0b.z, r0b.w};
        const float r1[8] = {r1a.x, r1a.y, r1a.z, r1a.w, r1b.x, r1b.y, r1b.z, r1b.w};

        float ll[4], lh[4], hl[4], hh[4];
#pragma unroll
        for (int p = 0; p < 4; ++p) {
            const float a = r0[2 * p];
            const float b = r0[2 * p + 1];
            const float c = r1[2 * p];
            const float d = r1[2 * p + 1];
            ll[p] = (a + b + c + d) * 0.5f;
            lh[p] = (a + b - c - d) * 0.5f;
            hl[p] = (a - b + c - d) * 0.5f;
            hh[p] = (a - b - c + d) * 0.5f;
        }

        // LL: [B, C, HO, WO]
        const long long ll_off = (((long long)bc * HO + i) * WO) + (jq << 2);
        *(float4*)(out + ll_off) = make_float4(ll[0], ll[1], ll[2], ll[3]);

        // high_freq: [B, 3, C, HO, WO], k=0:LH, 1:HL, 2:HH
        const int b_idx = bc >> 6;             // bc / 64
        const int c_idx = bc & 63;             // bc % 64
        const long long hf0 =
            HBASE + ((((long long)(b_idx * 3) * C_ + c_idx) * HO + i) * WO) + (jq << 2);
        *(float4*)(out + hf0)               = make_float4(lh[0], lh[1], lh[2], lh[3]);
        *(float4*)(out + hf0 + KSTRIDE)     = make_float4(hl[0], hl[1], hl[2], hl[3]);
        *(float4*)(out + hf0 + 2 * KSTRIDE) = make_float4(hh[0], hh[1], hh[2], hh[3]);
    }
}

extern "C" void kernel_launch(void* const* d_in, const int* in_sizes, int n_in,
                              void* d_out, int out_size, void* d_ws, size_t ws_size,
                              hipStream_t stream)
{
    const float* x = (const float*)d_in[0];
    float* out = (float*)d_out;

    const int threads = 256;
    const int blocks  = 4096;   // 4 grid-stride iters per thread; 2048 resident max
    haar_dwt2_kernel<<<blocks, threads, 0, stream>>>(x, out);
}

// Round 3
// 95.732 us; speedup vs baseline: 1.0984x; 1.0984x over previous
//
#include <hip/hip_runtime.h>

// x: [B=16, C=64, H=256, W=256] fp32
// out: LL [16,64,128,128] ++ high_freq [16,3,64,128,128]  (flat fp32)
//
// Single-shot mapping: thread t -> one 1x4 output quad (bc, i, jq).
//   t & 31        = jq   (quad col, 32 per row)
//   (t >> 5)&127  = i    (output row)
//   t >> 12       = bc   (b*64 + c)
// Reads 2x32B contiguous (rows 2i, 2i+1), writes 4x16B (LL,LH,HL,HH).
// All global accesses non-temporal (native ext_vector type — HIP's float4
// class is rejected by the builtin): pure stream, zero reuse, input alone
// equals L3 capacity.

typedef float fx4 __attribute__((ext_vector_type(4)));

#define B_  16
#define C_  64
#define HO  128
#define WO  128
#define WQ  (WO / 4)                            // 32
#define BC  (B_ * C_)                           // 1024
#define TOTAL_QUADS (BC * HO * WQ)              // 4,194,304
#define HBASE ((long long)BC * HO * WO)         // 16,777,216 (LL size)
#define KSTRIDE ((long long)C_ * HO * WO)       // 1,048,576

__global__ __launch_bounds__(256) void haar_dwt2_kernel(
    const float* __restrict__ x, float* __restrict__ out)
{
    const int t = blockIdx.x * 256 + threadIdx.x;   // < 4,194,304, fits int

    const int jq = t & 31;
    const int i  = (t >> 5) & 127;
    const int bc = t >> 12;

    const float* row0 = x + (((long long)bc * 256 + 2 * i) * 256) + (jq << 3);
    const float* row1 = row0 + 256;

    const fx4 r0a = __builtin_nontemporal_load((const fx4*)(row0));
    const fx4 r0b = __builtin_nontemporal_load((const fx4*)(row0 + 4));
    const fx4 r1a = __builtin_nontemporal_load((const fx4*)(row1));
    const fx4 r1b = __builtin_nontemporal_load((const fx4*)(row1 + 4));

    const float r0[8] = {r0a.x, r0a.y, r0a.z, r0a.w, r0b.x, r0b.y, r0b.z, r0b.w};
    const float r1[8] = {r1a.x, r1a.y, r1a.z, r1a.w, r1b.x, r1b.y, r1b.z, r1b.w};

    fx4 ll, lh, hl, hh;
#pragma unroll
    for (int p = 0; p < 4; ++p) {
        const float a = r0[2 * p];
        const float b = r0[2 * p + 1];
        const float c = r1[2 * p];
        const float d = r1[2 * p + 1];
        ll[p] = (a + b + c + d) * 0.5f;
        lh[p] = (a + b - c - d) * 0.5f;
        hl[p] = (a - b + c - d) * 0.5f;
        hh[p] = (a - b - c + d) * 0.5f;
    }

    // LL: [B, C, HO, WO]
    const long long ll_off = (((long long)bc * HO + i) * WO) + (jq << 2);
    __builtin_nontemporal_store(ll, (fx4*)(out + ll_off));

    // high_freq: [B, 3, C, HO, WO], k=0:LH, 1:HL, 2:HH
    const int b_idx = bc >> 6;
    const int c_idx = bc & 63;
    const long long hf0 =
        HBASE + ((((long long)(b_idx * 3) * C_ + c_idx) * HO + i) * WO) + (jq << 2);
    __builtin_nontemporal_store(lh, (fx4*)(out + hf0));
    __builtin_nontemporal_store(hl, (fx4*)(out + hf0 + KSTRIDE));
    __builtin_nontemporal_store(hh, (fx4*)(out + hf0 + 2 * KSTRIDE));
}

extern "C" void kernel_launch(void* const* d_in, const int* in_sizes, int n_in,
                              void* d_out, int out_size, void* d_ws, size_t ws_size,
                              hipStream_t stream)
{
    const float* x = (const float*)d_in[0];
    float* out = (float*)d_out;

    const int threads = 256;
    const int blocks  = TOTAL_QUADS / threads;   // 16384, exact
    haar_dwt2_kernel<<<blocks, threads, 0, stream>>>(x, out);
}

// Round 4
// 92.092 us; speedup vs baseline: 1.1419x; 1.0395x over previous
//
#include <hip/hip_runtime.h>

// x: [B=16, C=64, H=256, W=256] fp32
// out: LL [16,64,128,128] ++ high_freq [16,3,64,128,128]  (flat fp32)
//
// Dense-load variant: thread t -> one 2-col output pair (bc, i, jp).
//   t & 63        = jp   (col-pair idx, 64 per output row)
//   (t >> 6)&127  = i    (output row)
//   t >> 13       = bc   (b*64 + c)
// Each thread loads 16B contiguous from rows 2i and 2i+1 (input cols
// 4jp..4jp+3). A wave's 64 lanes cover one full 1KB input row perfectly
// dense per load instruction (lane l at byte l*16). Stores: 8B/lane,
// 512B dense per instruction. All accesses non-temporal (pure stream,
// input alone equals L3 capacity).

typedef float fx4 __attribute__((ext_vector_type(4)));
typedef float fx2 __attribute__((ext_vector_type(2)));

#define B_  16
#define C_  64
#define HO  128
#define WO  128
#define WP  (WO / 2)                            // 64 col-pairs per row
#define BC  (B_ * C_)                           // 1024
#define TOTAL_PAIRS (BC * HO * WP)              // 8,388,608
#define HBASE ((long long)BC * HO * WO)         // 16,777,216 (LL size)
#define KSTRIDE ((long long)C_ * HO * WO)       // 1,048,576

__global__ __launch_bounds__(256) void haar_dwt2_kernel(
    const float* __restrict__ x, float* __restrict__ out)
{
    const int t = blockIdx.x * 256 + threadIdx.x;   // < 8,388,608, fits int

    const int jp = t & 63;
    const int i  = (t >> 6) & 127;
    const int bc = t >> 13;

    // input cols 4jp..4jp+3 of rows 2i, 2i+1
    const float* row0 = x + (((long long)bc * 256 + 2 * i) * 256) + (jp << 2);
    const float* row1 = row0 + 256;

    const fx4 r0 = __builtin_nontemporal_load((const fx4*)(row0));
    const fx4 r1 = __builtin_nontemporal_load((const fx4*)(row1));

    fx2 ll, lh, hl, hh;
    {   // output col 2jp: a=r0.x b=r0.y c=r1.x d=r1.y
        const float s0 = r0.x + r0.y, d0 = r0.x - r0.y;
        const float s1 = r1.x + r1.y, d1 = r1.x - r1.y;
        ll.x = (s0 + s1) * 0.5f;
        lh.x = (s0 - s1) * 0.5f;
        hl.x = (d0 + d1) * 0.5f;
        hh.x = (d0 - d1) * 0.5f;
    }
    {   // output col 2jp+1: a=r0.z b=r0.w c=r1.z d=r1.w
        const float s0 = r0.z + r0.w, d0 = r0.z - r0.w;
        const float s1 = r1.z + r1.w, d1 = r1.z - r1.w;
        ll.y = (s0 + s1) * 0.5f;
        lh.y = (s0 - s1) * 0.5f;
        hl.y = (d0 + d1) * 0.5f;
        hh.y = (d0 - d1) * 0.5f;
    }

    // LL: [B, C, HO, WO]
    const long long ll_off = (((long long)bc * HO + i) * WO) + (jp << 1);
    __builtin_nontemporal_store(ll, (fx2*)(out + ll_off));

    // high_freq: [B, 3, C, HO, WO], k=0:LH, 1:HL, 2:HH
    const int b_idx = bc >> 6;
    const int c_idx = bc & 63;
    const long long hf0 =
        HBASE + ((((long long)(b_idx * 3) * C_ + c_idx) * HO + i) * WO) + (jp << 1);
    __builtin_nontemporal_store(lh, (fx2*)(out + hf0));
    __builtin_nontemporal_store(hl, (fx2*)(out + hf0 + KSTRIDE));
    __builtin_nontemporal_store(hh, (fx2*)(out + hf0 + 2 * KSTRIDE));
}

extern "C" void kernel_launch(void* const* d_in, const int* in_sizes, int n_in,
                              void* d_out, int out_size, void* d_ws, size_t ws_size,
                              hipStream_t stream)
{
    const float* x = (const float*)d_in[0];
    float* out = (float*)d_out;

    const int threads = 256;
    const int blocks  = TOTAL_PAIRS / threads;   // 32768, exact
    haar_dwt2_kernel<<<blocks, threads, 0, stream>>>(x, out);
}

// Round 5
// 91.403 us; speedup vs baseline: 1.1505x; 1.0075x over previous
//
#include <hip/hip_runtime.h>

// x: [B=16, C=64, H=256, W=256] fp32
// out: LL [16,64,128,128] ++ high_freq [16,3,64,128,128]  (flat fp32)
//
// R5: LDS-batched writes. Compute phase identical to R4 (dense 16B/lane NT
// loads, thread t -> output col-pair). Instead of 4x 8B scattered stores per
// thread (4 interleaved write streams x 512B bursts), each block stages its
// 4 subbands x 4 rows x 128 cols (8KB) in LDS; after one barrier each WAVE
// owns one subband and writes its 2KB contiguous region as two 1KB-dense
// fx4 NT stores -> one stream per wave, 1KB bursts, better DRAM page
// locality.
//
// Block mapping (grid 32768 x 256): t = blk*256 + tid
//   jp = t&63 (col-pair), i = (t>>6)&127, bc = t>>13
//   => per block: bc = blk>>5 (const), i0 = (blk*4)&127, rows i0..i0+3.

typedef float fx4 __attribute__((ext_vector_type(4)));
typedef float fx2 __attribute__((ext_vector_type(2)));

#define B_  16
#define C_  64
#define HO  128
#define WO  128
#define BC  (B_ * C_)                           // 1024
#define TOTAL_PAIRS (BC * HO * (WO / 2))        // 8,388,608
#define HBASE ((long long)BC * HO * WO)         // 16,777,216 (LL size)
#define KSTRIDE ((long long)C_ * HO * WO)       // 1,048,576

__global__ __launch_bounds__(256) void haar_dwt2_kernel(
    const float* __restrict__ x, float* __restrict__ out)
{
    __shared__ float lds[4 * 4 * 128];          // [subband][row 0..3][col 0..127]

    const int tid = threadIdx.x;
    const int jp  = tid & 63;                   // col-pair 0..63
    const int r   = tid >> 6;                   // local row 0..3 (== wave id)
    const int bc  = blockIdx.x >> 5;            // b*64 + c
    const int i0  = (blockIdx.x * 4) & 127;     // first output row of block
    const int i   = i0 + r;

    // ---- compute phase (same as R4) ----
    const float* row0 = x + (((long long)bc * 256 + 2 * i) * 256) + (jp << 2);
    const float* row1 = row0 + 256;

    const fx4 r0 = __builtin_nontemporal_load((const fx4*)(row0));
    const fx4 r1 = __builtin_nontemporal_load((const fx4*)(row1));

    fx2 ll, lh, hl, hh;
    {
        const float s0 = r0.x + r0.y, d0 = r0.x - r0.y;
        const float s1 = r1.x + r1.y, d1 = r1.x - r1.y;
        ll.x = (s0 + s1) * 0.5f;
        lh.x = (s0 - s1) * 0.5f;
        hl.x = (d0 + d1) * 0.5f;
        hh.x = (d0 - d1) * 0.5f;
    }
    {
        const float s0 = r0.z + r0.w, d0 = r0.z - r0.w;
        const float s1 = r1.z + r1.w, d1 = r1.z - r1.w;
        ll.y = (s0 + s1) * 0.5f;
        lh.y = (s0 - s1) * 0.5f;
        hl.y = (d0 + d1) * 0.5f;
        hh.y = (d0 - d1) * 0.5f;
    }

    // stage into LDS: lds[s][r][2jp..2jp+1]
    const int lbase = r * 128 + (jp << 1);
    *(fx2*)&lds[0 * 512 + lbase] = ll;
    *(fx2*)&lds[1 * 512 + lbase] = lh;
    *(fx2*)&lds[2 * 512 + lbase] = hl;
    *(fx2*)&lds[3 * 512 + lbase] = hh;

    __syncthreads();

    // ---- write phase: wave w owns subband w (0=LL, 1=LH, 2=HL, 3=HH) ----
    const int w    = r;                          // wave id
    const int lane = jp;                         // tid & 63

    const fx4 lo = *(const fx4*)&lds[w * 512 + (lane << 2)];
    const fx4 hi = *(const fx4*)&lds[w * 512 + 256 + (lane << 2)];

    long long gbase;
    if (w == 0) {
        gbase = ((long long)bc * HO + i0) * WO;                    // LL
    } else {
        const int b_idx = bc >> 6;
        const int c_idx = bc & 63;
        gbase = HBASE + ((((long long)(b_idx * 3 + (w - 1))) * C_ + c_idx) * HO + i0) * WO;
    }
    __builtin_nontemporal_store(lo, (fx4*)(out + gbase + (lane << 2)));
    __builtin_nontemporal_store(hi, (fx4*)(out + gbase + 256 + (lane << 2)));
}

extern "C" void kernel_launch(void* const* d_in, const int* in_sizes, int n_in,
                              void* d_out, int out_size, void* d_ws, size_t ws_size,
                              hipStream_t stream)
{
    const float* x = (const float*)d_in[0];
    float* out = (float*)d_out;

    const int threads = 256;
    const int blocks  = TOTAL_PAIRS / threads;   // 32768
    haar_dwt2_kernel<<<blocks, threads, 0, stream>>>(x, out);
}